// Round 4
// baseline (839.171 us; speedup 1.0000x reference)
//
#include <hip/hip_runtime.h>
#include <math.h>

typedef __bf16 bf16_t;
typedef __bf16 bf16x4 __attribute__((ext_vector_type(4)));
typedef __bf16 bf16x8 __attribute__((ext_vector_type(8)));
typedef _Float16 f16x4 __attribute__((ext_vector_type(4)));
typedef _Float16 f16x8 __attribute__((ext_vector_type(8)));
typedef float f32x4 __attribute__((ext_vector_type(4)));

#define MFMA_BF16 __builtin_amdgcn_mfma_f32_16x16x32_bf16
#define MFMA_F16  __builtin_amdgcn_mfma_f32_16x16x32_f16

// ---------- helpers ----------

__device__ __forceinline__ bf16_t to_bf16_rne(float x, float& rep) {
    unsigned u = __builtin_bit_cast(unsigned, x);
    unsigned r = u + 0x7fffu + ((u >> 16) & 1u);
    unsigned short h = (unsigned short)(r >> 16);
    rep = __builtin_bit_cast(float, ((unsigned)h) << 16);
    return __builtin_bit_cast(bf16_t, h);
}

__device__ __forceinline__ void g2l16(const void* g, void* l) {
    __builtin_amdgcn_global_load_lds(
        (const __attribute__((address_space(1))) unsigned int*)g,
        (__attribute__((address_space(3))) unsigned int*)l, 16, 0, 0);
}

// swizzled element offset of 16B-chunk (row r, chunk j in 0..7); rows are 128B.
// j ^= (r&7): involution, applied on pre-swizzled global src AND on ds_read.
__device__ __forceinline__ int lch(int r, int j) {
    return (r * 8 + (j ^ (r & 7))) * 8;
}

// stage one K-tile: A 256 rows x 128B (16384 el) + B 128 rows x 128B (8192 el).
// 6 global_load_lds per thread (4 A + 2 B). Linear LDS dest, swizzled source.
template <typename T>
__device__ __forceinline__ void stage3(const T* __restrict__ gA, long long ldA,
                                       const T* __restrict__ gB, long long ldB,
                                       T* buf, int tid) {
    int wid = tid >> 6, lane = tid & 63;
#pragma unroll
    for (int i = 0; i < 4; ++i) {
        int cb = i * 512 + wid * 64;
        int c = cb + lane;
        int r = c >> 3, j = (c & 7) ^ (r & 7);
        g2l16(gA + (long long)r * ldA + j * 8, buf + (size_t)cb * 8);
    }
#pragma unroll
    for (int i = 0; i < 2; ++i) {
        int cb = i * 512 + wid * 64;
        int c = cb + lane;
        int r = c >> 3, j = (c & 7) ^ (r & 7);
        g2l16(gB + (long long)r * ldB + j * 8, buf + 16384 + (size_t)cb * 8);
    }
}

// ---------- elementwise prep kernels ----------

// f32 [rows][1024] -> interleaved bf16 hi/lo: row stride 2048, 32-k blocks [32 hi|32 lo]
__global__ __launch_bounds__(256) void split_int_k(const float* __restrict__ in,
                                                   bf16_t* __restrict__ out,
                                                   long long n4) {
    long long i = (long long)blockIdx.x * 256 + threadIdx.x;
    if (i >= n4) return;
    f32x4 v = ((const f32x4*)in)[i];
    bf16x4 hv, lv;
#pragma unroll
    for (int j = 0; j < 4; ++j) {
        float rep;
        hv[j] = to_bf16_rne(v[j], rep);
        float res = v[j] - rep;
        float rep2;
        lv[j] = to_bf16_rne(res, rep2);
    }
    long long row = i >> 8;
    int k = (int)(i & 255) * 4;
    long long base = row * 2048 + ((k >> 5) << 6) + (k & 31);
    *(bf16x4*)(out + base) = hv;
    *(bf16x4*)(out + base + 32) = lv;
}

__global__ __launch_bounds__(256) void cast_f16_k(const float* __restrict__ in,
                                                  _Float16* __restrict__ o, long long n4) {
    long long i = (long long)blockIdx.x * 256 + threadIdx.x;
    if (i >= n4) return;
    f32x4 v = ((const f32x4*)in)[i];
    f16x4 h;
#pragma unroll
    for (int j = 0; j < 4; ++j) h[j] = (_Float16)v[j];
    ((f16x4*)o)[i] = h;
}

// ctx chunk [G][1024][1024] f32 -> ctxT [G][1024(d)][1024(k)] f16
__global__ __launch_bounds__(256) void transpose_ctx_k(const float* __restrict__ ctx,
                                                       _Float16* __restrict__ ctxT) {
    __shared__ _Float16 t[32][34];
    int b = blockIdx.z;
    int k0 = blockIdx.x * 32, d0 = blockIdx.y * 32;
    const float* src = ctx + ((long long)b * 1024 + k0) * 1024 + d0;
#pragma unroll
    for (int i = 0; i < 4; ++i) {
        int y = threadIdx.y + i * 8;
        t[y][threadIdx.x] = (_Float16)src[(long long)y * 1024 + threadIdx.x];
    }
    __syncthreads();
    _Float16* dst = ctxT + ((long long)b * 1024 + d0) * 1024 + k0;
#pragma unroll
    for (int i = 0; i < 4; ++i) {
        int y = threadIdx.y + i * 8;
        dst[(long long)y * 1024 + threadIdx.x] = t[threadIdx.x][y];
    }
}

// per-row masked softmax: w_k = m_k*exp(s_k - max)/sum  (fp32 in, f16 out)
__global__ __launch_bounds__(256) void masked_softmax_k(const float* __restrict__ s,
                                                        const int* __restrict__ m,
                                                        _Float16* __restrict__ w) {
    long long row = blockIdx.x;
    const float* sr = s + row * 1024;
    const int* mr = m + row * 1024;
    _Float16* wr_ = w + row * 1024;
    int t = threadIdx.x;
    int lane = t & 63, wid = t >> 6;
    float v[4];
    int mk[4];
    float mx = -3.0e38f;
#pragma unroll
    for (int i = 0; i < 4; ++i) {
        int idx = t + i * 256;
        v[i] = sr[idx];
        mk[i] = mr[idx];
        if (mk[i]) mx = fmaxf(mx, v[i]);
    }
#pragma unroll
    for (int off = 32; off; off >>= 1) mx = fmaxf(mx, __shfl_xor(mx, off));
    __shared__ float rm[4], rs[4];
    if (!lane) rm[wid] = mx;
    __syncthreads();
    mx = fmaxf(fmaxf(rm[0], rm[1]), fmaxf(rm[2], rm[3]));
    float sum = 0.f;
#pragma unroll
    for (int i = 0; i < 4; ++i) {
        float e = mk[i] ? expf(v[i] - mx) : 0.f;
        v[i] = e;
        sum += e;
    }
#pragma unroll
    for (int off = 32; off; off >>= 1) sum += __shfl_xor(sum, off);
    if (!lane) rs[wid] = sum;
    __syncthreads();
    sum = rs[0] + rs[1] + rs[2] + rs[3];
    float inv = sum > 0.f ? 1.0f / sum : 0.f;
#pragma unroll
    for (int i = 0; i < 4; ++i) wr_[t + i * 256] = (_Float16)(v[i] * inv);
}

// ---------- 256x128 3-buffer bf16x3 GEMM, prefetch distance 2 ----------
// A,B interleaved hi/lo rows of 2048 el, K=1024 (BK=32, NT=32). 8 waves 2x4,
// wave tile 128x32. One barrier/tile; vmcnt(6) counted; stage(t+2) after bar.
// EPI 0: f32 scores (ld 1024, +z*sC). EPI 1: qint interleaved + qf f16.
template <int EPI>
__global__ __launch_bounds__(512, 2) void gemm_x3_v2(
    const bf16_t* __restrict__ Aint, const bf16_t* __restrict__ Bint,
    long long sA, long long sB, long long sC, int nbx, int nby,
    float* __restrict__ Cs, bf16_t* __restrict__ Qint, _Float16* __restrict__ Qf) {
    __shared__ bf16_t lds[73728];   // 3 x 24576 el (48 KiB each)
    const int NT = 32;
    int tid = threadIdx.x, lane = tid & 63, wid = tid >> 6;
    int wr = wid >> 2, wc = wid & 3;
    int nwg = gridDim.x;
    int bid = blockIdx.x;
    int lid = (bid & 7) * (nwg >> 3) + (bid >> 3);
    int by = lid % nby;
    int t2 = lid / nby;
    int bx = t2 % nbx;
    int z = t2 / nbx;
    const bf16_t* At = Aint + (long long)z * sA + (long long)bx * 256 * 2048;
    const bf16_t* Bt = Bint + (long long)z * sB + (long long)by * 128 * 2048;
    stage3(At, 2048ll, Bt, 2048ll, lds, tid);
    stage3(At + 64, 2048ll, Bt + 64, 2048ll, lds + 24576, tid);
    f32x4 acc[8][2] = {};
    for (int t = 0; t < NT; ++t) {
        bf16_t* buf = lds + (size_t)(t % 3) * 24576;
        bf16_t* bufB = buf + 16384;
        if (t + 1 < NT) {
            asm volatile("s_waitcnt vmcnt(6)" ::: "memory");
        } else {
            asm volatile("s_waitcnt vmcnt(0)" ::: "memory");
        }
        __builtin_amdgcn_sched_barrier(0);
        __builtin_amdgcn_s_barrier();
        __builtin_amdgcn_sched_barrier(0);
        if (t + 2 < NT)
            stage3(At + (long long)(t + 2) * 64, 2048ll, Bt + (long long)(t + 2) * 64,
                   2048ll, lds + (size_t)((t + 2) % 3) * 24576, tid);
        bf16x8 bh[2], bl[2];
#pragma unroll
        for (int n = 0; n < 2; ++n) {
            int rB = wc * 32 + n * 16 + (lane & 15);
            bh[n] = *(const bf16x8*)(bufB + lch(rB, lane >> 4));
            bl[n] = *(const bf16x8*)(bufB + lch(rB, 4 + (lane >> 4)));
        }
#pragma unroll
        for (int g = 0; g < 2; ++g) {
            bf16x8 ah[4], al[4];
#pragma unroll
            for (int i = 0; i < 4; ++i) {
                int rA = wr * 128 + (g * 4 + i) * 16 + (lane & 15);
                ah[i] = *(const bf16x8*)(buf + lch(rA, lane >> 4));
                al[i] = *(const bf16x8*)(buf + lch(rA, 4 + (lane >> 4)));
            }
            __builtin_amdgcn_s_setprio(1);
#pragma unroll
            for (int i = 0; i < 4; ++i)
#pragma unroll
                for (int n = 0; n < 2; ++n) {
                    f32x4 a = acc[g * 4 + i][n];
                    a = MFMA_BF16(ah[i], bh[n], a, 0, 0, 0);
                    a = MFMA_BF16(ah[i], bl[n], a, 0, 0, 0);
                    a = MFMA_BF16(al[i], bh[n], a, 0, 0, 0);
                    acc[g * 4 + i][n] = a;
                }
            __builtin_amdgcn_s_setprio(0);
        }
    }
    int r0 = bx * 256 + wr * 128 + ((lane >> 4) << 2);
    int c0 = by * 128 + wc * 32 + (lane & 15);
#pragma unroll
    for (int m = 0; m < 8; ++m)
#pragma unroll
        for (int n = 0; n < 2; ++n)
#pragma unroll
            for (int j = 0; j < 4; ++j) {
                int r = r0 + m * 16 + j;
                int c = c0 + n * 16;
                float v = acc[m][n][j];
                if (EPI == 0) {
                    Cs[(long long)z * sC + (long long)r * 1024 + c] = v;
                } else {
                    float rep;
                    bf16_t hb = to_bf16_rne(v, rep);
                    float res = v - rep;
                    float rep2;
                    bf16_t lb = to_bf16_rne(res, rep2);
                    long long rb = (long long)r * 2048 + ((c >> 5) << 6) + (c & 31);
                    Qint[rb] = hb;
                    Qint[rb + 32] = lb;
                    Qf[(long long)r * 1024 + c] = (_Float16)v;
                }
            }
}

// ---------- 256x128 3-buffer f16 GEMM (BK=64), prefetch distance 2 ----------
// A rows K-contig (ldA), A-source switch at tile swt. B rows K-contig (ldB).
// EPI 0: f16 out (ld 1024, +z*sC). EPI 1: f32 tanh out (ld 1024).
template <int EPI>
__global__ __launch_bounds__(512, 2) void gemm_f16_v2(
    const _Float16* __restrict__ A1, const _Float16* __restrict__ A2,
    const _Float16* __restrict__ B,
    long long ldA, long long ldB, long long sA, long long sB, long long sC,
    int NT, int swt, int nbx, int nby,
    _Float16* __restrict__ Cm, float* __restrict__ Co) {
    __shared__ _Float16 lds[73728];
    int tid = threadIdx.x, lane = tid & 63, wid = tid >> 6;
    int wr = wid >> 2, wc = wid & 3;
    int nwg = gridDim.x;
    int bid = blockIdx.x;
    int lid = (bid & 7) * (nwg >> 3) + (bid >> 3);
    int by = lid % nby;
    int t2 = lid / nby;
    int bx = t2 % nbx;
    int z = t2 / nbx;
    const _Float16* A1t = A1 + (long long)z * sA + (long long)bx * 256 * ldA;
    const _Float16* A2t = A2 + (long long)bx * 256 * ldA;
    const _Float16* Bt = B + (long long)z * sB + (long long)by * 128 * ldB;
    stage3((0 < swt) ? A1t : A2t, ldA, Bt, ldB, lds, tid);
    stage3((1 < swt) ? A1t + 64 : A2t + (long long)(1 - swt) * 64, ldA, Bt + 64, ldB,
           lds + 24576, tid);
    f32x4 acc[8][2] = {};
    for (int t = 0; t < NT; ++t) {
        _Float16* buf = lds + (size_t)(t % 3) * 24576;
        _Float16* bufB = buf + 16384;
        if (t + 1 < NT) {
            asm volatile("s_waitcnt vmcnt(6)" ::: "memory");
        } else {
            asm volatile("s_waitcnt vmcnt(0)" ::: "memory");
        }
        __builtin_amdgcn_sched_barrier(0);
        __builtin_amdgcn_s_barrier();
        __builtin_amdgcn_sched_barrier(0);
        if (t + 2 < NT) {
            int tt = t + 2;
            const _Float16* gA =
                (tt < swt) ? A1t + (long long)tt * 64 : A2t + (long long)(tt - swt) * 64;
            stage3(gA, ldA, Bt + (long long)tt * 64, ldB,
                   lds + (size_t)(tt % 3) * 24576, tid);
        }
        f16x8 bfr[2][2];
#pragma unroll
        for (int n = 0; n < 2; ++n)
#pragma unroll
            for (int ks = 0; ks < 2; ++ks) {
                int rB = wc * 32 + n * 16 + (lane & 15);
                bfr[n][ks] = *(const f16x8*)(bufB + lch(rB, ks * 4 + (lane >> 4)));
            }
#pragma unroll
        for (int g = 0; g < 2; ++g) {
            f16x8 a[4][2];
#pragma unroll
            for (int i = 0; i < 4; ++i)
#pragma unroll
                for (int ks = 0; ks < 2; ++ks) {
                    int rA = wr * 128 + (g * 4 + i) * 16 + (lane & 15);
                    a[i][ks] = *(const f16x8*)(buf + lch(rA, ks * 4 + (lane >> 4)));
                }
            __builtin_amdgcn_s_setprio(1);
#pragma unroll
            for (int i = 0; i < 4; ++i)
#pragma unroll
                for (int n = 0; n < 2; ++n) {
                    f32x4 v = acc[g * 4 + i][n];
                    v = MFMA_F16(a[i][0], bfr[n][0], v, 0, 0, 0);
                    v = MFMA_F16(a[i][1], bfr[n][1], v, 0, 0, 0);
                    acc[g * 4 + i][n] = v;
                }
            __builtin_amdgcn_s_setprio(0);
        }
    }
    int r0 = bx * 256 + wr * 128 + ((lane >> 4) << 2);
    int c0 = by * 128 + wc * 32 + (lane & 15);
#pragma unroll
    for (int m = 0; m < 8; ++m)
#pragma unroll
        for (int n = 0; n < 2; ++n)
#pragma unroll
            for (int j = 0; j < 4; ++j) {
                int r = r0 + m * 16 + j;
                int c = c0 + n * 16;
                float v = acc[m][n][j];
                if (EPI == 0) {
                    Cm[(long long)z * sC + (long long)r * 1024 + c] = (_Float16)v;
                } else {
                    Co[(long long)r * 1024 + c] = tanhf(v);
                }
            }
}

// ---------- launch ----------

extern "C" void kernel_launch(void* const* d_in, const int* in_sizes, int n_in,
                              void* d_out, int out_size, void* d_ws, size_t ws_size,
                              hipStream_t stream) {
    const float* query = (const float*)d_in[0];
    const float* ctx = (const float*)d_in[1];
    const int* mask = (const int*)d_in[2];
    const float* Win = (const float*)d_in[3];
    const float* Wout = (const float*)d_in[4];
    float* outp = (float*)d_out;

    const long long MB = 1048576ll;
    int G = 1;
    if ((long long)ws_size >= 648 * MB) G = 32;
    else if ((long long)ws_size >= 328 * MB) G = 16;
    else if ((long long)ws_size >= 168 * MB) G = 8;
    else if ((long long)ws_size >= 88 * MB) G = 4;
    else if ((long long)ws_size >= 48 * MB) G = 2;

    char* p = (char*)d_ws;
    bf16_t* win_int = (bf16_t*)p; p += 4 * MB;     // [1024][2048] interleaved
    _Float16* woutf = (_Float16*)p; p += 4 * MB;   // [1024][2048]
    const long long R = (long long)G * 1024;
    bf16_t* qint = (bf16_t*)p; p += 4 * G * MB;    // [R][2048] interleaved
    _Float16* qf = (_Float16*)p; p += 2 * G * MB;  // [R][1024]
    bf16_t* ctx_int = (bf16_t*)p; p += 4 * G * MB; // [R][2048] interleaved
    _Float16* ctxT = (_Float16*)p; p += 2 * G * MB;
    _Float16* wf = (_Float16*)p; p += 2 * G * MB;
    _Float16* mixf = (_Float16*)p; p += 2 * G * MB;
    bf16_t* qs_int = (bf16_t*)p;                   // 4G MB (dead before scores)
    float* scores = (float*)p;                     // 4G MB, same region

    const long long LD = 1048576ll;

    split_int_k<<<1024, 256, 0, stream>>>(Win, win_int, 262144ll);
    cast_f16_k<<<2048, 256, 0, stream>>>(Wout, woutf, 524288ll);

    for (int b0 = 0; b0 < 32; b0 += G) {
        const float* qsrc = query + (long long)b0 * LD;
        const float* csrc = ctx + (long long)b0 * LD;
        split_int_k<<<(int)R, 256, 0, stream>>>(qsrc, qs_int, R * 256);
        // GEMM1: q = query @ Win^T (bf16x3) -> qint (interleaved) + qf (f16)
        gemm_x3_v2<1><<<32 * G, 512, 0, stream>>>(
            qs_int, win_int, 0, 0, 0, 4 * G, 8, nullptr, qint, qf);
        split_int_k<<<(int)R, 256, 0, stream>>>(csrc, ctx_int, R * 256);
        transpose_ctx_k<<<dim3(32, 32, G), dim3(32, 8, 1), 0, stream>>>(csrc, ctxT);
        // GEMM2: scores = q @ ctx^T (bf16x3)
        gemm_x3_v2<0><<<32 * G, 512, 0, stream>>>(
            qint, ctx_int, 2097152ll, 2097152ll, 1048576ll, 4, 8,
            scores, nullptr, nullptr);
        masked_softmax_k<<<(int)R, 256, 0, stream>>>(
            scores, mask + (long long)b0 * 1024 * 1024, wf);
        // GEMM3: mix = w @ ctxT^T (f16)
        gemm_f16_v2<0><<<32 * G, 512, 0, stream>>>(
            wf, wf, ctxT, 1024ll, 1024ll, 1048576ll, 1048576ll, 1048576ll,
            16, 1 << 20, 4, 8, mixf, nullptr);
        // GEMM4: out = tanh(mix @ W1^T + q @ W2^T), K=2048, A-switch at tile 16
        gemm_f16_v2<1><<<32 * G, 512, 0, stream>>>(
            mixf, qf, woutf, 1024ll, 2048ll, 0, 0, 0,
            32, 16, 4 * G, 8, nullptr, outp + (long long)b0 * LD);
    }
}

// Round 5
// 830.989 us; speedup vs baseline: 1.0098x; 1.0098x over previous
//
#include <hip/hip_runtime.h>
#include <math.h>

typedef __bf16 bf16_t;
typedef __bf16 bf16x4 __attribute__((ext_vector_type(4)));
typedef __bf16 bf16x8 __attribute__((ext_vector_type(8)));
typedef _Float16 f16x4 __attribute__((ext_vector_type(4)));
typedef _Float16 f16x8 __attribute__((ext_vector_type(8)));
typedef float f32x4 __attribute__((ext_vector_type(4)));
typedef float f32x16 __attribute__((ext_vector_type(16)));

#define MFMA32B __builtin_amdgcn_mfma_f32_32x32x16_bf16
#define MFMA32F __builtin_amdgcn_mfma_f32_32x32x16_f16

// ---------- helpers ----------

__device__ __forceinline__ bf16_t to_bf16_rne(float x, float& rep) {
    unsigned u = __builtin_bit_cast(unsigned, x);
    unsigned r = u + 0x7fffu + ((u >> 16) & 1u);
    unsigned short h = (unsigned short)(r >> 16);
    rep = __builtin_bit_cast(float, ((unsigned)h) << 16);
    return __builtin_bit_cast(bf16_t, h);
}

__device__ __forceinline__ void g2l16(const void* g, void* l) {
    __builtin_amdgcn_global_load_lds(
        (const __attribute__((address_space(1))) unsigned int*)g,
        (__attribute__((address_space(3))) unsigned int*)l, 16, 0, 0);
}

// swizzled element offset of 16B-chunk (row r in 0..255, chunk j in 0..7);
// rows are 128B. j ^= (r&7): involution, applied on pre-swizzled global
// source AND on every ds_read.
__device__ __forceinline__ int lch(int r, int j) {
    return (r * 8 + (j ^ (r & 7))) * 8;
}

// stage one K-tile: A 256 rows x 128B + B 256 rows x 128B. 8 loads/thread.
template <typename T>
__device__ __forceinline__ void stage2(const T* __restrict__ gA, long long ldA,
                                       const T* __restrict__ gB, long long ldB,
                                       T* buf, int tid) {
    int wid = tid >> 6, lane = tid & 63;
#pragma unroll
    for (int i = 0; i < 4; ++i) {
        int cb = i * 512 + wid * 64;
        int c = cb + lane;
        int r = c >> 3, j = (c & 7) ^ (r & 7);
        g2l16(gA + (long long)r * ldA + j * 8, buf + (size_t)cb * 8);
    }
#pragma unroll
    for (int i = 0; i < 4; ++i) {
        int cb = i * 512 + wid * 64;
        int c = cb + lane;
        int r = c >> 3, j = (c & 7) ^ (r & 7);
        g2l16(gB + (long long)r * ldB + j * 8, buf + 16384 + (size_t)cb * 8);
    }
}

// ---------- elementwise prep kernels ----------

// f32 [rows][1024] -> interleaved bf16 hi/lo: row stride 2048, 32-k blocks [32 hi|32 lo]
__global__ __launch_bounds__(256) void split_int_k(const float* __restrict__ in,
                                                   bf16_t* __restrict__ out,
                                                   long long n4) {
    long long i = (long long)blockIdx.x * 256 + threadIdx.x;
    if (i >= n4) return;
    f32x4 v = ((const f32x4*)in)[i];
    bf16x4 hv, lv;
#pragma unroll
    for (int j = 0; j < 4; ++j) {
        float rep;
        hv[j] = to_bf16_rne(v[j], rep);
        float res = v[j] - rep;
        float rep2;
        lv[j] = to_bf16_rne(res, rep2);
    }
    long long row = i >> 8;
    int k = (int)(i & 255) * 4;
    long long base = row * 2048 + ((k >> 5) << 6) + (k & 31);
    *(bf16x4*)(out + base) = hv;
    *(bf16x4*)(out + base + 32) = lv;
}

__global__ __launch_bounds__(256) void cast_f16_k(const float* __restrict__ in,
                                                  _Float16* __restrict__ o, long long n4) {
    long long i = (long long)blockIdx.x * 256 + threadIdx.x;
    if (i >= n4) return;
    f32x4 v = ((const f32x4*)in)[i];
    f16x4 h;
#pragma unroll
    for (int j = 0; j < 4; ++j) h[j] = (_Float16)v[j];
    ((f16x4*)o)[i] = h;
}

// ctx chunk [G][1024][1024] f32 -> ctxT [G][1024(d)][1024(k)] f16
__global__ __launch_bounds__(256) void transpose_ctx_k(const float* __restrict__ ctx,
                                                       _Float16* __restrict__ ctxT) {
    __shared__ _Float16 t[32][34];
    int b = blockIdx.z;
    int k0 = blockIdx.x * 32, d0 = blockIdx.y * 32;
    const float* src = ctx + ((long long)b * 1024 + k0) * 1024 + d0;
#pragma unroll
    for (int i = 0; i < 4; ++i) {
        int y = threadIdx.y + i * 8;
        t[y][threadIdx.x] = (_Float16)src[(long long)y * 1024 + threadIdx.x];
    }
    __syncthreads();
    _Float16* dst = ctxT + ((long long)b * 1024 + d0) * 1024 + k0;
#pragma unroll
    for (int i = 0; i < 4; ++i) {
        int y = threadIdx.y + i * 8;
        dst[(long long)y * 1024 + threadIdx.x] = t[threadIdx.x][y];
    }
}

// per-row masked softmax: w_k = m_k*exp(s_k - max)/sum  (fp32 in, f16 out)
__global__ __launch_bounds__(256) void masked_softmax_k(const float* __restrict__ s,
                                                        const int* __restrict__ m,
                                                        _Float16* __restrict__ w) {
    long long row = blockIdx.x;
    const float* sr = s + row * 1024;
    const int* mr = m + row * 1024;
    _Float16* wr_ = w + row * 1024;
    int t = threadIdx.x;
    int lane = t & 63, wid = t >> 6;
    float v[4];
    int mk[4];
    float mx = -3.0e38f;
#pragma unroll
    for (int i = 0; i < 4; ++i) {
        int idx = t + i * 256;
        v[i] = sr[idx];
        mk[i] = mr[idx];
        if (mk[i]) mx = fmaxf(mx, v[i]);
    }
#pragma unroll
    for (int off = 32; off; off >>= 1) mx = fmaxf(mx, __shfl_xor(mx, off));
    __shared__ float rm[4], rs[4];
    if (!lane) rm[wid] = mx;
    __syncthreads();
    mx = fmaxf(fmaxf(rm[0], rm[1]), fmaxf(rm[2], rm[3]));
    float sum = 0.f;
#pragma unroll
    for (int i = 0; i < 4; ++i) {
        float e = mk[i] ? expf(v[i] - mx) : 0.f;
        v[i] = e;
        sum += e;
    }
#pragma unroll
    for (int off = 32; off; off >>= 1) sum += __shfl_xor(sum, off);
    if (!lane) rs[wid] = sum;
    __syncthreads();
    sum = rs[0] + rs[1] + rs[2] + rs[3];
    float inv = sum > 0.f ? 1.0f / sum : 0.f;
#pragma unroll
    for (int i = 0; i < 4; ++i) wr_[t + i * 256] = (_Float16)(v[i] * inv);
}

// ---------- 256x256 dbuf bf16x3 GEMM, 32x32x16 MFMA ----------
// A,B interleaved hi/lo rows of 2048 el, K=1024 real (NT=32 tiles of 32 real k).
// 8 waves (2x4), wave tile 128x64: 4 m-frags x 2 n-frags of 32x32.
// EPI 0: f32 scores (ld 1024, +z*sC). EPI 1: qint interleaved + qf f16.
template <int EPI>
__global__ __launch_bounds__(512, 2) void gemm_x3_w(
    const bf16_t* __restrict__ Aint, const bf16_t* __restrict__ Bint,
    long long sA, long long sB, long long sC, int nbx, int nby,
    float* __restrict__ Cs, bf16_t* __restrict__ Qint, _Float16* __restrict__ Qf) {
    __shared__ bf16_t lds[65536];
    const int NT = 32;
    int tid = threadIdx.x, lane = tid & 63, wid = tid >> 6;
    int wr = wid >> 2, wc = wid & 3;
    int nwg = gridDim.x;
    int bid = blockIdx.x;
    int lid = (bid & 7) * (nwg >> 3) + (bid >> 3);   // XCD-contiguous remap
    int by = lid % nby;
    int t2 = lid / nby;
    int bx = t2 % nbx;
    int z = t2 / nbx;
    const bf16_t* At = Aint + (long long)z * sA + (long long)bx * 256 * 2048;
    const bf16_t* Bt = Bint + (long long)z * sB + (long long)by * 256 * 2048;
    stage2(At, 2048ll, Bt, 2048ll, lds, tid);
    stage2(At + 64, 2048ll, Bt + 64, 2048ll, lds + 32768, tid);
    f32x16 acc[4][2] = {};
    int l31 = lane & 31, lh = lane >> 5;
    for (int t = 0; t < NT; ++t) {
        bf16_t* buf = lds + (size_t)(t & 1) * 32768;
        bf16_t* bufB = buf + 16384;
        if (t < NT - 1) {
            asm volatile("s_waitcnt vmcnt(8)" ::: "memory");
        } else {
            asm volatile("s_waitcnt vmcnt(0)" ::: "memory");
        }
        __builtin_amdgcn_sched_barrier(0);
        __builtin_amdgcn_s_barrier();
        __builtin_amdgcn_sched_barrier(0);
        bf16x8 bh[2][2], bl[2][2];
#pragma unroll
        for (int n = 0; n < 2; ++n) {
            int rB = wc * 64 + n * 32 + l31;
#pragma unroll
            for (int ks = 0; ks < 2; ++ks) {
                bh[n][ks] = *(const bf16x8*)(bufB + lch(rB, ks * 2 + lh));
                bl[n][ks] = *(const bf16x8*)(bufB + lch(rB, 4 + ks * 2 + lh));
            }
        }
        bf16x8 ah[2][2], al[2][2];
#pragma unroll
        for (int mm = 0; mm < 2; ++mm) {
            int rA = wr * 128 + mm * 32 + l31;
#pragma unroll
            for (int ks = 0; ks < 2; ++ks) {
                ah[mm][ks] = *(const bf16x8*)(buf + lch(rA, ks * 2 + lh));
                al[mm][ks] = *(const bf16x8*)(buf + lch(rA, 4 + ks * 2 + lh));
            }
        }
        __builtin_amdgcn_s_setprio(1);
#pragma unroll
        for (int ks = 0; ks < 2; ++ks)
#pragma unroll
            for (int mm = 0; mm < 2; ++mm)
#pragma unroll
                for (int n = 0; n < 2; ++n)
                    acc[mm][n] = MFMA32B(ah[mm][ks], bh[n][ks], acc[mm][n], 0, 0, 0);
#pragma unroll
        for (int ks = 0; ks < 2; ++ks)
#pragma unroll
            for (int mm = 0; mm < 2; ++mm)
#pragma unroll
                for (int n = 0; n < 2; ++n)
                    acc[mm][n] = MFMA32B(ah[mm][ks], bl[n][ks], acc[mm][n], 0, 0, 0);
#pragma unroll
        for (int ks = 0; ks < 2; ++ks)
#pragma unroll
            for (int mm = 0; mm < 2; ++mm)
#pragma unroll
                for (int n = 0; n < 2; ++n)
                    acc[mm][n] = MFMA32B(al[mm][ks], bh[n][ks], acc[mm][n], 0, 0, 0);
        __builtin_amdgcn_s_setprio(0);
        bf16x8 ah2[2][2], al2[2][2];
#pragma unroll
        for (int mm = 0; mm < 2; ++mm) {
            int rA = wr * 128 + (2 + mm) * 32 + l31;
#pragma unroll
            for (int ks = 0; ks < 2; ++ks) {
                ah2[mm][ks] = *(const bf16x8*)(buf + lch(rA, ks * 2 + lh));
                al2[mm][ks] = *(const bf16x8*)(buf + lch(rA, 4 + ks * 2 + lh));
            }
        }
        asm volatile("s_waitcnt lgkmcnt(0)" ::: "memory");
        __builtin_amdgcn_sched_barrier(0);
        __builtin_amdgcn_s_barrier();
        __builtin_amdgcn_sched_barrier(0);
        if (t + 2 < NT)
            stage2(At + (long long)(t + 2) * 64, 2048ll, Bt + (long long)(t + 2) * 64,
                   2048ll, buf, tid);
        __builtin_amdgcn_s_setprio(1);
#pragma unroll
        for (int ks = 0; ks < 2; ++ks)
#pragma unroll
            for (int mm = 0; mm < 2; ++mm)
#pragma unroll
                for (int n = 0; n < 2; ++n)
                    acc[2 + mm][n] = MFMA32B(ah2[mm][ks], bh[n][ks], acc[2 + mm][n], 0, 0, 0);
#pragma unroll
        for (int ks = 0; ks < 2; ++ks)
#pragma unroll
            for (int mm = 0; mm < 2; ++mm)
#pragma unroll
                for (int n = 0; n < 2; ++n)
                    acc[2 + mm][n] = MFMA32B(ah2[mm][ks], bl[n][ks], acc[2 + mm][n], 0, 0, 0);
#pragma unroll
        for (int ks = 0; ks < 2; ++ks)
#pragma unroll
            for (int mm = 0; mm < 2; ++mm)
#pragma unroll
                for (int n = 0; n < 2; ++n)
                    acc[2 + mm][n] = MFMA32B(al2[mm][ks], bh[n][ks], acc[2 + mm][n], 0, 0, 0);
        __builtin_amdgcn_s_setprio(0);
    }
    // C layout (32x32): col = lane&31, row = (reg&3) + 8*(reg>>2) + 4*(lane>>5)
    int r0 = bx * 256 + wr * 128 + 4 * lh;
    int c0 = by * 256 + wc * 64 + l31;
#pragma unroll
    for (int m = 0; m < 4; ++m)
#pragma unroll
        for (int n = 0; n < 2; ++n)
#pragma unroll
            for (int reg = 0; reg < 16; ++reg) {
                int r = r0 + m * 32 + (reg & 3) + 8 * (reg >> 2);
                int c = c0 + n * 32;
                float v = acc[m][n][reg];
                if (EPI == 0) {
                    Cs[(long long)z * sC + (long long)r * 1024 + c] = v;
                } else {
                    float rep;
                    bf16_t hb = to_bf16_rne(v, rep);
                    float res = v - rep;
                    float rep2;
                    bf16_t lb = to_bf16_rne(res, rep2);
                    long long rb = (long long)r * 2048 + ((c >> 5) << 6) + (c & 31);
                    Qint[rb] = hb;
                    Qint[rb + 32] = lb;
                    Qf[(long long)r * 1024 + c] = (_Float16)v;
                }
            }
}

// ---------- 256x256 dbuf f16 GEMM, 32x32x16 MFMA (BK=64 real) ----------
// A rows K-contig (ldA), A-source switch at tile swt. B rows K-contig (ldB).
// EPI 0: f16 out (ld 1024, +z*sC). EPI 1: f32 tanh out (ld 1024).
template <int EPI>
__global__ __launch_bounds__(512, 2) void gemm_f16_w(
    const _Float16* __restrict__ A1, const _Float16* __restrict__ A2,
    const _Float16* __restrict__ B,
    long long ldA, long long ldB, long long sA, long long sB, long long sC,
    int NT, int swt, int nbx, int nby,
    _Float16* __restrict__ Cm, float* __restrict__ Co) {
    __shared__ _Float16 lds[65536];
    int tid = threadIdx.x, lane = tid & 63, wid = tid >> 6;
    int wr = wid >> 2, wc = wid & 3;
    int nwg = gridDim.x;
    int bid = blockIdx.x;
    int lid = (bid & 7) * (nwg >> 3) + (bid >> 3);
    int by = lid % nby;
    int t2 = lid / nby;
    int bx = t2 % nbx;
    int z = t2 / nbx;
    const _Float16* A1t = A1 + (long long)z * sA + (long long)bx * 256 * ldA;
    const _Float16* A2t = A2 + (long long)bx * 256 * ldA;
    const _Float16* Bt = B + (long long)z * sB + (long long)by * 256 * ldB;
    stage2((0 < swt) ? A1t : A2t, ldA, Bt, ldB, lds, tid);
    stage2((1 < swt) ? A1t + 64 : A2t + (long long)(1 - swt) * 64, ldA, Bt + 64, ldB,
           lds + 32768, tid);
    f32x16 acc[4][2] = {};
    int l31 = lane & 31, lh = lane >> 5;
    for (int t = 0; t < NT; ++t) {
        _Float16* buf = lds + (size_t)(t & 1) * 32768;
        _Float16* bufB = buf + 16384;
        if (t < NT - 1) {
            asm volatile("s_waitcnt vmcnt(8)" ::: "memory");
        } else {
            asm volatile("s_waitcnt vmcnt(0)" ::: "memory");
        }
        __builtin_amdgcn_sched_barrier(0);
        __builtin_amdgcn_s_barrier();
        __builtin_amdgcn_sched_barrier(0);
        f16x8 bfr[2][4];
#pragma unroll
        for (int n = 0; n < 2; ++n) {
            int rB = wc * 64 + n * 32 + l31;
#pragma unroll
            for (int ks = 0; ks < 4; ++ks)
                bfr[n][ks] = *(const f16x8*)(bufB + lch(rB, ks * 2 + lh));
        }
        f16x8 a[2][4];
#pragma unroll
        for (int mm = 0; mm < 2; ++mm) {
            int rA = wr * 128 + mm * 32 + l31;
#pragma unroll
            for (int ks = 0; ks < 4; ++ks)
                a[mm][ks] = *(const f16x8*)(buf + lch(rA, ks * 2 + lh));
        }
        __builtin_amdgcn_s_setprio(1);
#pragma unroll
        for (int ks = 0; ks < 4; ++ks)
#pragma unroll
            for (int mm = 0; mm < 2; ++mm)
#pragma unroll
                for (int n = 0; n < 2; ++n)
                    acc[mm][n] = MFMA32F(a[mm][ks], bfr[n][ks], acc[mm][n], 0, 0, 0);
        __builtin_amdgcn_s_setprio(0);
        f16x8 a2[2][4];
#pragma unroll
        for (int mm = 0; mm < 2; ++mm) {
            int rA = wr * 128 + (2 + mm) * 32 + l31;
#pragma unroll
            for (int ks = 0; ks < 4; ++ks)
                a2[mm][ks] = *(const f16x8*)(buf + lch(rA, ks * 2 + lh));
        }
        asm volatile("s_waitcnt lgkmcnt(0)" ::: "memory");
        __builtin_amdgcn_sched_barrier(0);
        __builtin_amdgcn_s_barrier();
        __builtin_amdgcn_sched_barrier(0);
        if (t + 2 < NT) {
            int tt = t + 2;
            const _Float16* gA =
                (tt < swt) ? A1t + (long long)tt * 64 : A2t + (long long)(tt - swt) * 64;
            stage2(gA, ldA, Bt + (long long)tt * 64, ldB,
                   lds + (size_t)(tt & 1) * 32768, tid);
        }
        __builtin_amdgcn_s_setprio(1);
#pragma unroll
        for (int ks = 0; ks < 4; ++ks)
#pragma unroll
            for (int mm = 0; mm < 2; ++mm)
#pragma unroll
                for (int n = 0; n < 2; ++n)
                    acc[2 + mm][n] = MFMA32F(a2[mm][ks], bfr[n][ks], acc[2 + mm][n], 0, 0, 0);
        __builtin_amdgcn_s_setprio(0);
    }
    int r0 = bx * 256 + wr * 128 + 4 * lh;
    int c0 = by * 256 + wc * 64 + l31;
#pragma unroll
    for (int m = 0; m < 4; ++m)
#pragma unroll
        for (int n = 0; n < 2; ++n)
#pragma unroll
            for (int reg = 0; reg < 16; ++reg) {
                int r = r0 + m * 32 + (reg & 3) + 8 * (reg >> 2);
                int c = c0 + n * 32;
                float v = acc[m][n][reg];
                if (EPI == 0) {
                    Cm[(long long)z * sC + (long long)r * 1024 + c] = (_Float16)v;
                } else {
                    Co[(long long)r * 1024 + c] = tanhf(v);
                }
            }
}

// ---------- launch ----------

extern "C" void kernel_launch(void* const* d_in, const int* in_sizes, int n_in,
                              void* d_out, int out_size, void* d_ws, size_t ws_size,
                              hipStream_t stream) {
    const float* query = (const float*)d_in[0];
    const float* ctx = (const float*)d_in[1];
    const int* mask = (const int*)d_in[2];
    const float* Win = (const float*)d_in[3];
    const float* Wout = (const float*)d_in[4];
    float* outp = (float*)d_out;

    const long long MB = 1048576ll;
    // footprint: 8 + 16G MB (ctx_int slab reused by wf+mixf; qs_int by scores)
    int G = 1;
    if ((long long)ws_size >= 520 * MB) G = 32;
    else if ((long long)ws_size >= 264 * MB) G = 16;
    else if ((long long)ws_size >= 136 * MB) G = 8;
    else if ((long long)ws_size >= 72 * MB) G = 4;
    else if ((long long)ws_size >= 40 * MB) G = 2;

    char* p = (char*)d_ws;
    bf16_t* win_int = (bf16_t*)p; p += 4 * MB;     // [1024][2048] interleaved
    _Float16* woutf = (_Float16*)p; p += 4 * MB;   // [1024][2048]
    const long long R = (long long)G * 1024;
    bf16_t* qint = (bf16_t*)p; p += 4 * G * MB;    // [R][2048] interleaved
    _Float16* qf = (_Float16*)p; p += 2 * G * MB;  // [R][1024]
    // slabA: ctx_int [R][2048] interleaved; after GEMM2 reused as wf|mixf
    char* slabA = p; p += 4 * G * MB;
    bf16_t* ctx_int = (bf16_t*)slabA;
    _Float16* wf = (_Float16*)slabA;               // [R][1024] (over ctx_int, dead)
    _Float16* mixf = (_Float16*)(slabA + 2 * G * MB);
    _Float16* ctxT = (_Float16*)p; p += 2 * G * MB;
    // slabC: qs_int (dead after GEMM1) then scores f32
    char* slabC = p;
    bf16_t* qs_int = (bf16_t*)slabC;
    float* scores = (float*)slabC;

    const long long LD = 1048576ll;

    split_int_k<<<1024, 256, 0, stream>>>(Win, win_int, 262144ll);
    cast_f16_k<<<2048, 256, 0, stream>>>(Wout, woutf, 524288ll);

    for (int b0 = 0; b0 < 32; b0 += G) {
        const float* qsrc = query + (long long)b0 * LD;
        const float* csrc = ctx + (long long)b0 * LD;
        split_int_k<<<(int)R, 256, 0, stream>>>(qsrc, qs_int, R * 256);
        // GEMM1: q = query @ Win^T (bf16x3) -> qint (interleaved) + qf (f16)
        gemm_x3_w<1><<<16 * G, 512, 0, stream>>>(
            qs_int, win_int, 0, 0, 0, 4 * G, 4, nullptr, qint, qf);
        split_int_k<<<(int)R, 256, 0, stream>>>(csrc, ctx_int, R * 256);
        transpose_ctx_k<<<dim3(32, 32, G), dim3(32, 8, 1), 0, stream>>>(csrc, ctxT);
        // GEMM2: scores = q @ ctx^T (bf16x3)
        gemm_x3_w<0><<<16 * G, 512, 0, stream>>>(
            qint, ctx_int, 2097152ll, 2097152ll, 1048576ll, 4, 4,
            scores, nullptr, nullptr);
        masked_softmax_k<<<(int)R, 256, 0, stream>>>(
            scores, mask + (long long)b0 * 1024 * 1024, wf);
        // GEMM3: mix = w @ ctxT^T (f16)
        gemm_f16_w<0><<<16 * G, 512, 0, stream>>>(
            wf, wf, ctxT, 1024ll, 1024ll, 1048576ll, 1048576ll, 1048576ll,
            16, 1 << 20, 4, 4, mixf, nullptr);
        // GEMM4: out = tanh(mix @ W1^T + q @ W2^T), K=2048, A-switch at tile 16
        gemm_f16_w<1><<<16 * G, 512, 0, stream>>>(
            mixf, qf, woutf, 1024ll, 2048ll, 0, 0, 0,
            32, 16, 4 * G, 4, nullptr, outp + (long long)b0 * LD);
    }
}

// Round 6
// 778.819 us; speedup vs baseline: 1.0775x; 1.0670x over previous
//
#include <hip/hip_runtime.h>
#include <math.h>

typedef __bf16 bf16_t;
typedef __bf16 bf16x4 __attribute__((ext_vector_type(4)));
typedef __bf16 bf16x8 __attribute__((ext_vector_type(8)));
typedef _Float16 f16x4 __attribute__((ext_vector_type(4)));
typedef _Float16 f16x8 __attribute__((ext_vector_type(8)));
typedef float f32x4 __attribute__((ext_vector_type(4)));
typedef int i32x4 __attribute__((ext_vector_type(4)));

#define MFMA_BF16 __builtin_amdgcn_mfma_f32_16x16x32_bf16
#define MFMA_F16  __builtin_amdgcn_mfma_f32_16x16x32_f16

// ---------- helpers ----------

__device__ __forceinline__ bf16_t to_bf16_rne(float x, float& rep) {
    unsigned u = __builtin_bit_cast(unsigned, x);
    unsigned r = u + 0x7fffu + ((u >> 16) & 1u);
    unsigned short h = (unsigned short)(r >> 16);
    rep = __builtin_bit_cast(float, ((unsigned)h) << 16);
    return __builtin_bit_cast(bf16_t, h);
}

__device__ __forceinline__ void g2l16(const void* g, void* l) {
    __builtin_amdgcn_global_load_lds(
        (const __attribute__((address_space(1))) unsigned int*)g,
        (__attribute__((address_space(3))) unsigned int*)l, 16, 0, 0);
}

// swizzled element offset of 16B-chunk (row r in 0..255, chunk j in 0..7);
// rows are 128B. j ^= (r&7): involution, applied on pre-swizzled global
// source AND on every ds_read. 16-row read spans -> 2-way (free) bank aliasing.
__device__ __forceinline__ int lch(int r, int j) {
    return (r * 8 + (j ^ (r & 7))) * 8;
}

// stage one K-tile: A 256 rows x 128B + B 256 rows x 128B. 8 loads/thread.
template <typename T>
__device__ __forceinline__ void stage2(const T* __restrict__ gA, long long ldA,
                                       const T* __restrict__ gB, long long ldB,
                                       T* buf, int tid) {
    int wid = tid >> 6, lane = tid & 63;
#pragma unroll
    for (int i = 0; i < 4; ++i) {
        int cb = i * 512 + wid * 64;
        int c = cb + lane;
        int r = c >> 3, j = (c & 7) ^ (r & 7);
        g2l16(gA + (long long)r * ldA + j * 8, buf + (size_t)cb * 8);
    }
#pragma unroll
    for (int i = 0; i < 4; ++i) {
        int cb = i * 512 + wid * 64;
        int c = cb + lane;
        int r = c >> 3, j = (c & 7) ^ (r & 7);
        g2l16(gB + (long long)r * ldB + j * 8, buf + 16384 + (size_t)cb * 8);
    }
}

// ---------- elementwise prep kernels ----------

// f32 [rows][1024] -> interleaved bf16 hi/lo: row stride 2048, 32-k blocks [32 hi|32 lo]
__global__ __launch_bounds__(256) void split_int_k(const float* __restrict__ in,
                                                   bf16_t* __restrict__ out,
                                                   long long n4) {
    long long i = (long long)blockIdx.x * 256 + threadIdx.x;
    if (i >= n4) return;
    f32x4 v = ((const f32x4*)in)[i];
    bf16x4 hv, lv;
#pragma unroll
    for (int j = 0; j < 4; ++j) {
        float rep;
        hv[j] = to_bf16_rne(v[j], rep);
        float res = v[j] - rep;
        float rep2;
        lv[j] = to_bf16_rne(res, rep2);
    }
    long long row = i >> 8;
    int k = (int)(i & 255) * 4;
    long long base = row * 2048 + ((k >> 5) << 6) + (k & 31);
    *(bf16x4*)(out + base) = hv;
    *(bf16x4*)(out + base + 32) = lv;
}

__global__ __launch_bounds__(256) void cast_f16_k(const float* __restrict__ in,
                                                  _Float16* __restrict__ o, long long n4) {
    long long i = (long long)blockIdx.x * 256 + threadIdx.x;
    if (i >= n4) return;
    f32x4 v = ((const f32x4*)in)[i];
    f16x4 h;
#pragma unroll
    for (int j = 0; j < 4; ++j) h[j] = (_Float16)v[j];
    ((f16x4*)o)[i] = h;
}

// fused: ctx chunk [G][1024][1024] f32 -> ctx_int (interleaved hi/lo bf16, rows 2048)
//        AND ctxT [G][1024(d)][1024(k)] f16   (reads ctx ONCE)
__global__ __launch_bounds__(256) void prep_ctx_k(const float* __restrict__ ctx,
                                                  bf16_t* __restrict__ ctx_int,
                                                  _Float16* __restrict__ ctxT) {
    __shared__ _Float16 tl[32][33];
    int b = blockIdx.z;
    int k0 = blockIdx.x * 32, d0 = blockIdx.y * 32;
    const float* src = ctx + ((long long)b * 1024 + k0) * 1024 + d0;
    int x = threadIdx.x, y = threadIdx.y;  // 32 x 8
#pragma unroll
    for (int i = 0; i < 4; ++i) {
        int k = y + i * 8;
        float v = src[(long long)k * 1024 + x];
        float rep;
        bf16_t hb = to_bf16_rne(v, rep);
        float rep2;
        bf16_t lb = to_bf16_rne(v - rep, rep2);
        long long rb = ((long long)b * 1024 + k0 + k) * 2048 + d0 * 2 + x;
        ctx_int[rb] = hb;
        ctx_int[rb + 32] = lb;
        tl[x][k] = (_Float16)v;
    }
    __syncthreads();
    _Float16* dst = ctxT + ((long long)b * 1024 + d0) * 1024 + k0;
#pragma unroll
    for (int i = 0; i < 4; ++i) {
        int dd = y + i * 8;
        dst[(long long)dd * 1024 + x] = tl[dd][x];
    }
}

// per-row masked softmax: w_k = m_k*exp(s_k - max)/sum  (fp32 in, f16 out)
// vectorized: 4 contiguous elems/thread
__global__ __launch_bounds__(256) void masked_softmax_k(const float* __restrict__ s,
                                                        const int* __restrict__ m,
                                                        _Float16* __restrict__ w) {
    long long row = blockIdx.x;
    const f32x4* sr = (const f32x4*)(s + row * 1024);
    const i32x4* mr = (const i32x4*)(m + row * 1024);
    f16x4* wr_ = (f16x4*)(w + row * 1024);
    int t = threadIdx.x;
    int lane = t & 63, wid = t >> 6;
    f32x4 v = sr[t];
    i32x4 mk = mr[t];
    float mx = -3.0e38f;
#pragma unroll
    for (int i = 0; i < 4; ++i)
        if (mk[i]) mx = fmaxf(mx, v[i]);
#pragma unroll
    for (int off = 32; off; off >>= 1) mx = fmaxf(mx, __shfl_xor(mx, off));
    __shared__ float rm[4], rs[4];
    if (!lane) rm[wid] = mx;
    __syncthreads();
    mx = fmaxf(fmaxf(rm[0], rm[1]), fmaxf(rm[2], rm[3]));
    float sum = 0.f;
    f32x4 e;
#pragma unroll
    for (int i = 0; i < 4; ++i) {
        e[i] = mk[i] ? expf(v[i] - mx) : 0.f;
        sum += e[i];
    }
#pragma unroll
    for (int off = 32; off; off >>= 1) sum += __shfl_xor(sum, off);
    if (!lane) rs[wid] = sum;
    __syncthreads();
    sum = rs[0] + rs[1] + rs[2] + rs[3];
    float inv = sum > 0.f ? 1.0f / sum : 0.f;
    f16x4 o;
#pragma unroll
    for (int i = 0; i < 4; ++i) o[i] = (_Float16)(e[i] * inv);
    wr_[t] = o;
}

// ---------- 256x256 dbuf bf16x3 GEMM (round-3 proven structure) ----------
// A,B: interleaved hi/lo pair layout, rows of 2048 elements, K=1024 (BK=32).
// C = Ah*Bh^T + Ah*Bl^T + Al*Bh^T. 8 waves (2x4), dbuf LDS 128 KiB,
// counted vmcnt(8), raw barriers, swizzled reads.
// EPI 0: f32 scores (ld 1024, +z*sC). EPI 1: qint interleaved + qf f16.
template <int EPI>
__global__ __launch_bounds__(512, 2) void gemm_x3_256(
    const bf16_t* __restrict__ Aint, const bf16_t* __restrict__ Bint,
    long long sA, long long sB, long long sC, int nbx, int nby,
    float* __restrict__ Cs, bf16_t* __restrict__ Qint, _Float16* __restrict__ Qf) {
    __shared__ bf16_t lds[65536];
    const int NT = 32;
    int tid = threadIdx.x, lane = tid & 63, wid = tid >> 6;
    int wr = wid >> 2, wc = wid & 3;
    int nwg = gridDim.x;
    int bid = blockIdx.x;
    int lid = (bid & 7) * (nwg >> 3) + (bid >> 3);   // XCD-contiguous remap
    int by = lid % nby;
    int t2 = lid / nby;
    int bx = t2 % nbx;
    int z = t2 / nbx;
    const bf16_t* At = Aint + (long long)z * sA + (long long)bx * 256 * 2048;
    const bf16_t* Bt = Bint + (long long)z * sB + (long long)by * 256 * 2048;
    stage2(At, 2048ll, Bt, 2048ll, lds, tid);
    stage2(At + 64, 2048ll, Bt + 64, 2048ll, lds + 32768, tid);
    f32x4 acc[8][4] = {};
    for (int t = 0; t < NT; ++t) {
        bf16_t* buf = lds + (size_t)(t & 1) * 32768;
        bf16_t* bufB = buf + 16384;
        if (t < NT - 1) {
            asm volatile("s_waitcnt vmcnt(8)" ::: "memory");
        } else {
            asm volatile("s_waitcnt vmcnt(0)" ::: "memory");
        }
        __builtin_amdgcn_sched_barrier(0);
        __builtin_amdgcn_s_barrier();
        __builtin_amdgcn_sched_barrier(0);
        bf16x8 bh[4], bl[4];
#pragma unroll
        for (int n = 0; n < 4; ++n) {
            int rB = wc * 64 + n * 16 + (lane & 15);
            bh[n] = *(const bf16x8*)(bufB + lch(rB, lane >> 4));
            bl[n] = *(const bf16x8*)(bufB + lch(rB, 4 + (lane >> 4)));
        }
#pragma unroll
        for (int p = 0; p < 3; ++p) {
            bf16x8 ah[2], al[2];
#pragma unroll
            for (int i = 0; i < 2; ++i) {
                int rA = wr * 128 + (p * 2 + i) * 16 + (lane & 15);
                ah[i] = *(const bf16x8*)(buf + lch(rA, lane >> 4));
                al[i] = *(const bf16x8*)(buf + lch(rA, 4 + (lane >> 4)));
            }
            __builtin_amdgcn_s_setprio(1);
#pragma unroll
            for (int i = 0; i < 2; ++i)
#pragma unroll
                for (int n = 0; n < 4; ++n) {
                    f32x4 a = acc[p * 2 + i][n];
                    a = MFMA_BF16(ah[i], bh[n], a, 0, 0, 0);
                    a = MFMA_BF16(ah[i], bl[n], a, 0, 0, 0);
                    a = MFMA_BF16(al[i], bh[n], a, 0, 0, 0);
                    acc[p * 2 + i][n] = a;
                }
            __builtin_amdgcn_s_setprio(0);
        }
        bf16x8 ah3[2], al3[2];
#pragma unroll
        for (int i = 0; i < 2; ++i) {
            int rA = wr * 128 + (6 + i) * 16 + (lane & 15);
            ah3[i] = *(const bf16x8*)(buf + lch(rA, lane >> 4));
            al3[i] = *(const bf16x8*)(buf + lch(rA, 4 + (lane >> 4)));
        }
        asm volatile("s_waitcnt lgkmcnt(0)" ::: "memory");
        __builtin_amdgcn_sched_barrier(0);
        __builtin_amdgcn_s_barrier();
        __builtin_amdgcn_sched_barrier(0);
        if (t + 2 < NT)
            stage2(At + (long long)(t + 2) * 64, 2048ll, Bt + (long long)(t + 2) * 64,
                   2048ll, buf, tid);
        __builtin_amdgcn_s_setprio(1);
#pragma unroll
        for (int i = 0; i < 2; ++i)
#pragma unroll
            for (int n = 0; n < 4; ++n) {
                f32x4 a = acc[6 + i][n];
                a = MFMA_BF16(ah3[i], bh[n], a, 0, 0, 0);
                a = MFMA_BF16(ah3[i], bl[n], a, 0, 0, 0);
                a = MFMA_BF16(al3[i], bh[n], a, 0, 0, 0);
                acc[6 + i][n] = a;
            }
        __builtin_amdgcn_s_setprio(0);
    }
    int r0 = bx * 256 + wr * 128 + ((lane >> 4) << 2);
    int c0 = by * 256 + wc * 64 + (lane & 15);
#pragma unroll
    for (int m = 0; m < 8; ++m)
#pragma unroll
        for (int n = 0; n < 4; ++n)
#pragma unroll
            for (int j = 0; j < 4; ++j) {
                int r = r0 + m * 16 + j;
                int c = c0 + n * 16;
                float v = acc[m][n][j];
                if (EPI == 0) {
                    Cs[(long long)z * sC + (long long)r * 1024 + c] = v;
                } else {
                    float rep;
                    bf16_t hb = to_bf16_rne(v, rep);
                    float res = v - rep;
                    float rep2;
                    bf16_t lb = to_bf16_rne(res, rep2);
                    long long rb = (long long)r * 2048 + ((c >> 5) << 6) + (c & 31);
                    Qint[rb] = hb;
                    Qint[rb + 32] = lb;
                    Qf[(long long)r * 1024 + c] = (_Float16)v;
                }
            }
}

// ---------- 256x256 dbuf f16 GEMM (round-3 proven structure, BK=64) ----------
// A rows K-contig (ldA), optional A-source switch at tile swt. B rows K-contig.
// EPI 0: f16 out (ld 1024, +z*sC). EPI 1: f32 tanh out (ld 1024).
template <int EPI>
__global__ __launch_bounds__(512, 2) void gemm_f16_256(
    const _Float16* __restrict__ A1, const _Float16* __restrict__ A2,
    const _Float16* __restrict__ B,
    long long ldA, long long ldB, long long sA, long long sB, long long sC,
    int NT, int swt, int nbx, int nby,
    _Float16* __restrict__ Cm, float* __restrict__ Co) {
    __shared__ _Float16 lds[65536];
    int tid = threadIdx.x, lane = tid & 63, wid = tid >> 6;
    int wr = wid >> 2, wc = wid & 3;
    int nwg = gridDim.x;
    int bid = blockIdx.x;
    int lid = (bid & 7) * (nwg >> 3) + (bid >> 3);
    int by = lid % nby;
    int t2 = lid / nby;
    int bx = t2 % nbx;
    int z = t2 / nbx;
    const _Float16* A1t = A1 + (long long)z * sA + (long long)bx * 256 * ldA;
    const _Float16* A2t = A2 + (long long)bx * 256 * ldA;
    const _Float16* Bt = B + (long long)z * sB + (long long)by * 256 * ldB;
    stage2((0 < swt) ? A1t : A2t, ldA, Bt, ldB, lds, tid);
    stage2((1 < swt) ? A1t + 64 : A2t + (long long)(1 - swt) * 64, ldA, Bt + 64, ldB,
           lds + 32768, tid);
    f32x4 acc[8][4] = {};
    for (int t = 0; t < NT; ++t) {
        _Float16* buf = lds + (size_t)(t & 1) * 32768;
        _Float16* bufB = buf + 16384;
        if (t < NT - 1) {
            asm volatile("s_waitcnt vmcnt(8)" ::: "memory");
        } else {
            asm volatile("s_waitcnt vmcnt(0)" ::: "memory");
        }
        __builtin_amdgcn_sched_barrier(0);
        __builtin_amdgcn_s_barrier();
        __builtin_amdgcn_sched_barrier(0);
        f16x8 bfr[4][2];
#pragma unroll
        for (int n = 0; n < 4; ++n)
#pragma unroll
            for (int ks = 0; ks < 2; ++ks) {
                int rB = wc * 64 + n * 16 + (lane & 15);
                bfr[n][ks] = *(const f16x8*)(bufB + lch(rB, ks * 4 + (lane >> 4)));
            }
#pragma unroll
        for (int p = 0; p < 3; ++p) {
            f16x8 a[2][2];
#pragma unroll
            for (int i = 0; i < 2; ++i)
#pragma unroll
                for (int ks = 0; ks < 2; ++ks) {
                    int rA = wr * 128 + (p * 2 + i) * 16 + (lane & 15);
                    a[i][ks] = *(const f16x8*)(buf + lch(rA, ks * 4 + (lane >> 4)));
                }
            __builtin_amdgcn_s_setprio(1);
#pragma unroll
            for (int i = 0; i < 2; ++i)
#pragma unroll
                for (int n = 0; n < 4; ++n) {
                    f32x4 v = acc[p * 2 + i][n];
                    v = MFMA_F16(a[i][0], bfr[n][0], v, 0, 0, 0);
                    v = MFMA_F16(a[i][1], bfr[n][1], v, 0, 0, 0);
                    acc[p * 2 + i][n] = v;
                }
            __builtin_amdgcn_s_setprio(0);
        }
        f16x8 a3[2][2];
#pragma unroll
        for (int i = 0; i < 2; ++i)
#pragma unroll
            for (int ks = 0; ks < 2; ++ks) {
                int rA = wr * 128 + (6 + i) * 16 + (lane & 15);
                a3[i][ks] = *(const f16x8*)(buf + lch(rA, ks * 4 + (lane >> 4)));
            }
        asm volatile("s_waitcnt lgkmcnt(0)" ::: "memory");
        __builtin_amdgcn_sched_barrier(0);
        __builtin_amdgcn_s_barrier();
        __builtin_amdgcn_sched_barrier(0);
        if (t + 2 < NT) {
            int tt = t + 2;
            const _Float16* gA =
                (tt < swt) ? A1t + (long long)tt * 64 : A2t + (long long)(tt - swt) * 64;
            stage2(gA, ldA, Bt + (long long)tt * 64, ldB,
                   lds + (size_t)(tt & 1) * 32768, tid);
        }
        __builtin_amdgcn_s_setprio(1);
#pragma unroll
        for (int i = 0; i < 2; ++i)
#pragma unroll
            for (int n = 0; n < 4; ++n) {
                f32x4 v = acc[6 + i][n];
                v = MFMA_F16(a3[i][0], bfr[n][0], v, 0, 0, 0);
                v = MFMA_F16(a3[i][1], bfr[n][1], v, 0, 0, 0);
                acc[6 + i][n] = v;
            }
        __builtin_amdgcn_s_setprio(0);
    }
    int r0 = bx * 256 + wr * 128 + ((lane >> 4) << 2);
    int c0 = by * 256 + wc * 64 + (lane & 15);
#pragma unroll
    for (int m = 0; m < 8; ++m)
#pragma unroll
        for (int n = 0; n < 4; ++n)
#pragma unroll
            for (int j = 0; j < 4; ++j) {
                int r = r0 + m * 16 + j;
                int c = c0 + n * 16;
                float v = acc[m][n][j];
                if (EPI == 0) {
                    Cm[(long long)z * sC + (long long)r * 1024 + c] = (_Float16)v;
                } else {
                    Co[(long long)r * 1024 + c] = tanhf(v);
                }
            }
}

// ---------- launch ----------

extern "C" void kernel_launch(void* const* d_in, const int* in_sizes, int n_in,
                              void* d_out, int out_size, void* d_ws, size_t ws_size,
                              hipStream_t stream) {
    const float* query = (const float*)d_in[0];
    const float* ctx = (const float*)d_in[1];
    const int* mask = (const int*)d_in[2];
    const float* Win = (const float*)d_in[3];
    const float* Wout = (const float*)d_in[4];
    float* outp = (float*)d_out;

    const long long MB = 1048576ll;
    // footprint: exactly 16G MiB (weights overlaid into dead slab regions).
    int G = 1;
    if ((long long)ws_size >= 512 * MB) G = 32;
    else if ((long long)ws_size >= 256 * MB) G = 16;
    else if ((long long)ws_size >= 128 * MB) G = 8;
    else if ((long long)ws_size >= 64 * MB) G = 4;
    else if ((long long)ws_size >= 32 * MB) G = 2;

    char* p = (char*)d_ws;
    const long long R = (long long)G * 1024;   // rows per chunk
    bf16_t* qint = (bf16_t*)p; p += 4 * G * MB;    // [R][2048] interleaved
    _Float16* qf = (_Float16*)p; p += 2 * G * MB;  // [R][1024]
    // slabA (4G MiB): win_int (4 MiB, GEMM1) -> ctx_int [R][2048] (GEMM2)
    //                 -> wf [R][1024] (lower 2G) + mixf [R][1024] (upper 2G)
    char* slabA = p; p += 4 * G * MB;
    bf16_t* win_int = (bf16_t*)slabA;
    bf16_t* ctx_int = (bf16_t*)slabA;
    _Float16* wf = (_Float16*)slabA;
    _Float16* mixf = (_Float16*)(slabA + 2 * G * MB);
    _Float16* ctxT = (_Float16*)p; p += 2 * G * MB;
    // slabC (4G MiB): qs_int (GEMM1 A) -> scores f32 (GEMM2/softmax) -> woutf (GEMM4 B)
    char* slabC = p;
    bf16_t* qs_int = (bf16_t*)slabC;
    float* scores = (float*)slabC;
    _Float16* woutf = (_Float16*)slabC;

    const long long LD = 1048576ll;  // 1024*1024 elements

    for (int b0 = 0; b0 < 32; b0 += G) {
        const float* qsrc = query + (long long)b0 * LD;
        const float* csrc = ctx + (long long)b0 * LD;
        // weights + query prep (win_int lives in slabA until prep_ctx overwrites it)
        split_int_k<<<1024, 256, 0, stream>>>(Win, win_int, 262144ll);
        split_int_k<<<(int)R, 256, 0, stream>>>(qsrc, qs_int, R * 256);
        // GEMM1: q = query @ Win^T (bf16x3) -> qint (interleaved) + qf (f16)
        gemm_x3_256<1><<<16 * G, 512, 0, stream>>>(
            qs_int, win_int, 0, 0, 0, 4 * G, 4, nullptr, qint, qf);
        // fused ctx prep: ctx_int (over win_int, dead) + ctxT, reads ctx once
        prep_ctx_k<<<dim3(32, 32, G), dim3(32, 8, 1), 0, stream>>>(csrc, ctx_int, ctxT);
        // GEMM2: scores = q @ ctx^T (bf16x3) -> scores (over qs_int, dead)
        gemm_x3_256<0><<<16 * G, 512, 0, stream>>>(
            qint, ctx_int, 2097152ll, 2097152ll, 1048576ll, 4, 4,
            scores, nullptr, nullptr);
        // softmax -> wf (over ctx_int lower half, dead)
        masked_softmax_k<<<(int)R, 256, 0, stream>>>(
            scores, mask + (long long)b0 * 1024 * 1024, wf);
        // Wout cast -> woutf (over scores, dead)
        cast_f16_k<<<2048, 256, 0, stream>>>(Wout, woutf, 524288ll);
        // GEMM3: mix = w @ ctxT^T (f16) -> mixf (over ctx_int upper half, dead)
        gemm_f16_256<0><<<16 * G, 512, 0, stream>>>(
            wf, wf, ctxT, 1024ll, 1024ll, 1048576ll, 1048576ll, 1048576ll,
            16, 1 << 20, 4, 4, mixf, nullptr);
        // GEMM4: out = tanh(mix @ W1^T + q @ W2^T), K=2048, A-switch at tile 16
        gemm_f16_256<1><<<16 * G, 512, 0, stream>>>(
            mixf, qf, woutf, 1024ll, 2048ll, 0, 0, 0,
            32, 16, 4 * G, 4, nullptr, outp + (long long)b0 * LD);
    }
}

// Round 7
// 762.654 us; speedup vs baseline: 1.1003x; 1.0212x over previous
//
#include <hip/hip_runtime.h>
#include <math.h>

typedef __bf16 bf16_t;
typedef __bf16 bf16x4 __attribute__((ext_vector_type(4)));
typedef __bf16 bf16x8 __attribute__((ext_vector_type(8)));
typedef _Float16 f16x4 __attribute__((ext_vector_type(4)));
typedef _Float16 f16x8 __attribute__((ext_vector_type(8)));
typedef float f32x4 __attribute__((ext_vector_type(4)));
typedef int i32x4 __attribute__((ext_vector_type(4)));

#define MFMA_BF16 __builtin_amdgcn_mfma_f32_16x16x32_bf16
#define MFMA_F16  __builtin_amdgcn_mfma_f32_16x16x32_f16

// phase sync: barrier, drain own ds_reads, pin, boost
#define P_PRE                                         \
    __builtin_amdgcn_sched_barrier(0);                \
    __builtin_amdgcn_s_barrier();                     \
    asm volatile("s_waitcnt lgkmcnt(0)" ::: "memory");\
    __builtin_amdgcn_sched_barrier(0);                \
    __builtin_amdgcn_s_setprio(1)
#define P_POST                                        \
    __builtin_amdgcn_s_setprio(0);                    \
    __builtin_amdgcn_sched_barrier(0);                \
    __builtin_amdgcn_s_barrier()

// ---------- helpers ----------

__device__ __forceinline__ bf16_t to_bf16_rne(float x, float& rep) {
    unsigned u = __builtin_bit_cast(unsigned, x);
    unsigned r = u + 0x7fffu + ((u >> 16) & 1u);
    unsigned short h = (unsigned short)(r >> 16);
    rep = __builtin_bit_cast(float, ((unsigned)h) << 16);
    return __builtin_bit_cast(bf16_t, h);
}

__device__ __forceinline__ void g2l16(const void* g, void* l) {
    __builtin_amdgcn_global_load_lds(
        (const __attribute__((address_space(1))) unsigned int*)g,
        (__attribute__((address_space(3))) unsigned int*)l, 16, 0, 0);
}

// swizzled element offset of 16B-chunk (row r in 0..255, chunk j in 0..7);
// rows are 128B. j ^= (r&7): involution, applied on pre-swizzled global
// source AND on every ds_read. 16-row read spans -> 2-way (free) bank aliasing.
__device__ __forceinline__ int lch(int r, int j) {
    return (r * 8 + (j ^ (r & 7))) * 8;
}

// stage A half-tile (256 rows x 128B) into buf[0:16384); 4 loads/thread
template <typename T>
__device__ __forceinline__ void stageA4(const T* __restrict__ gA, long long ldA,
                                        T* buf, int tid) {
    int wid = tid >> 6, lane = tid & 63;
#pragma unroll
    for (int i = 0; i < 4; ++i) {
        int cb = i * 512 + wid * 64;
        int c = cb + lane;
        int r = c >> 3, j = (c & 7) ^ (r & 7);
        g2l16(gA + (long long)r * ldA + j * 8, buf + (size_t)cb * 8);
    }
}

// stage B half-tile into buf[16384:32768); 4 loads/thread
template <typename T>
__device__ __forceinline__ void stageB4(const T* __restrict__ gB, long long ldB,
                                        T* buf, int tid) {
    int wid = tid >> 6, lane = tid & 63;
#pragma unroll
    for (int i = 0; i < 4; ++i) {
        int cb = i * 512 + wid * 64;
        int c = cb + lane;
        int r = c >> 3, j = (c & 7) ^ (r & 7);
        g2l16(gB + (long long)r * ldB + j * 8, buf + 16384 + (size_t)cb * 8);
    }
}

template <typename T>
__device__ __forceinline__ void stage2(const T* __restrict__ gA, long long ldA,
                                       const T* __restrict__ gB, long long ldB,
                                       T* buf, int tid) {
    stageA4(gA, ldA, buf, tid);
    stageB4(gB, ldB, buf, tid);
}

// ---------- elementwise prep kernels ----------

// f32 [rows][1024] -> interleaved bf16 hi/lo: row stride 2048, 32-k blocks [32 hi|32 lo]
__global__ __launch_bounds__(256) void split_int_k(const float* __restrict__ in,
                                                   bf16_t* __restrict__ out,
                                                   long long n4) {
    long long i = (long long)blockIdx.x * 256 + threadIdx.x;
    if (i >= n4) return;
    f32x4 v = ((const f32x4*)in)[i];
    bf16x4 hv, lv;
#pragma unroll
    for (int j = 0; j < 4; ++j) {
        float rep;
        hv[j] = to_bf16_rne(v[j], rep);
        float res = v[j] - rep;
        float rep2;
        lv[j] = to_bf16_rne(res, rep2);
    }
    long long row = i >> 8;
    int k = (int)(i & 255) * 4;
    long long base = row * 2048 + ((k >> 5) << 6) + (k & 31);
    *(bf16x4*)(out + base) = hv;
    *(bf16x4*)(out + base + 32) = lv;
}

__global__ __launch_bounds__(256) void cast_f16_k(const float* __restrict__ in,
                                                  _Float16* __restrict__ o, long long n4) {
    long long i = (long long)blockIdx.x * 256 + threadIdx.x;
    if (i >= n4) return;
    f32x4 v = ((const f32x4*)in)[i];
    f16x4 h;
#pragma unroll
    for (int j = 0; j < 4; ++j) h[j] = (_Float16)v[j];
    ((f16x4*)o)[i] = h;
}

// fused: ctx chunk [G][1024][1024] f32 -> ctx_int (interleaved hi/lo bf16, rows 2048)
//        AND ctxT [G][1024(d)][1024(k)] f16   (reads ctx ONCE)
__global__ __launch_bounds__(256) void prep_ctx_k(const float* __restrict__ ctx,
                                                  bf16_t* __restrict__ ctx_int,
                                                  _Float16* __restrict__ ctxT) {
    __shared__ _Float16 tl[32][33];
    int b = blockIdx.z;
    int k0 = blockIdx.x * 32, d0 = blockIdx.y * 32;
    const float* src = ctx + ((long long)b * 1024 + k0) * 1024 + d0;
    int x = threadIdx.x, y = threadIdx.y;  // 32 x 8
#pragma unroll
    for (int i = 0; i < 4; ++i) {
        int k = y + i * 8;
        float v = src[(long long)k * 1024 + x];
        float rep;
        bf16_t hb = to_bf16_rne(v, rep);
        float rep2;
        bf16_t lb = to_bf16_rne(v - rep, rep2);
        long long rb = ((long long)b * 1024 + k0 + k) * 2048 + d0 * 2 + x;
        ctx_int[rb] = hb;
        ctx_int[rb + 32] = lb;
        tl[x][k] = (_Float16)v;
    }
    __syncthreads();
    _Float16* dst = ctxT + ((long long)b * 1024 + d0) * 1024 + k0;
#pragma unroll
    for (int i = 0; i < 4; ++i) {
        int dd = y + i * 8;
        dst[(long long)dd * 1024 + x] = tl[dd][x];
    }
}

// per-row masked softmax: w_k = m_k*exp(s_k - max)/sum  (fp32 in, f16 out)
__global__ __launch_bounds__(256) void masked_softmax_k(const float* __restrict__ s,
                                                        const int* __restrict__ m,
                                                        _Float16* __restrict__ w) {
    long long row = blockIdx.x;
    const f32x4* sr = (const f32x4*)(s + row * 1024);
    const i32x4* mr = (const i32x4*)(m + row * 1024);
    f16x4* wr_ = (f16x4*)(w + row * 1024);
    int t = threadIdx.x;
    int lane = t & 63, wid = t >> 6;
    f32x4 v = sr[t];
    i32x4 mk = mr[t];
    float mx = -3.0e38f;
#pragma unroll
    for (int i = 0; i < 4; ++i)
        if (mk[i]) mx = fmaxf(mx, v[i]);
#pragma unroll
    for (int off = 32; off; off >>= 1) mx = fmaxf(mx, __shfl_xor(mx, off));
    __shared__ float rm[4], rs[4];
    if (!lane) rm[wid] = mx;
    __syncthreads();
    mx = fmaxf(fmaxf(rm[0], rm[1]), fmaxf(rm[2], rm[3]));
    float sum = 0.f;
    f32x4 e;
#pragma unroll
    for (int i = 0; i < 4; ++i) {
        e[i] = mk[i] ? expf(v[i] - mx) : 0.f;
        sum += e[i];
    }
#pragma unroll
    for (int off = 32; off; off >>= 1) sum += __shfl_xor(sum, off);
    if (!lane) rs[wid] = sum;
    __syncthreads();
    sum = rs[0] + rs[1] + rs[2] + rs[3];
    float inv = sum > 0.f ? 1.0f / sum : 0.f;
    f16x4 o;
#pragma unroll
    for (int i = 0; i < 4; ++i) o[i] = (_Float16)(e[i] * inv);
    wr_[t] = o;
}

// ---------- 256x256 dbuf bf16x3 GEMM, 4-phase interleave ----------
// A,B: interleaved hi/lo pair layout, rows of 2048 elements, K=1024 (BK=32).
// Per K-tile: P0{read B + m01 | MFMA m01} P1{read m2345 | MFMA m23}
// P2{read m67, stage B(t+2) | MFMA m45} P3{stage A(t+2), vmcnt(8) | MFMA m67}.
// B-half overwrite safe after P0's drain+bar; A-half after P2's. vmcnt(8)
// at P3 = "tile t+1's 8 loads complete"; never 0 until tail.
// EPI 0: f32 scores (ld 1024, +z*sC). EPI 1: qint interleaved + qf f16.
template <int EPI>
__global__ __launch_bounds__(512, 2) void gemm_x3_256(
    const bf16_t* __restrict__ Aint, const bf16_t* __restrict__ Bint,
    long long sA, long long sB, long long sC, int nbx, int nby,
    float* __restrict__ Cs, bf16_t* __restrict__ Qint, _Float16* __restrict__ Qf) {
    __shared__ bf16_t lds[65536];
    const int NT = 32;
    int tid = threadIdx.x, lane = tid & 63, wid = tid >> 6;
    int wr = wid >> 2, wc = wid & 3;
    int nwg = gridDim.x;
    int bid = blockIdx.x;
    int lid = (bid & 7) * (nwg >> 3) + (bid >> 3);   // XCD-contiguous remap
    int by = lid % nby;
    int t2_ = lid / nby;
    int bx = t2_ % nbx;
    int z = t2_ / nbx;
    const bf16_t* At = Aint + (long long)z * sA + (long long)bx * 256 * 2048;
    const bf16_t* Bt = Bint + (long long)z * sB + (long long)by * 256 * 2048;
    stage2(At, 2048ll, Bt, 2048ll, lds, tid);
    stage2(At + 64, 2048ll, Bt + 64, 2048ll, lds + 32768, tid);
    f32x4 acc[8][4] = {};
    int l15 = lane & 15, l4 = lane >> 4;
    asm volatile("s_waitcnt vmcnt(8)" ::: "memory");
    __builtin_amdgcn_sched_barrier(0);
    __builtin_amdgcn_s_barrier();
    for (int t = 0; t < NT; ++t) {
        bf16_t* buf = lds + (size_t)(t & 1) * 32768;
        bf16_t* bufB = buf + 16384;
        const bf16_t* At2 = At + (long long)(t + 2) * 64;
        const bf16_t* Bt2 = Bt + (long long)(t + 2) * 64;
        bool st = (t + 2 < NT);
        // ---- P0: read B all + A m0,m1; MFMA m0,m1 ----
        bf16x8 bh[4], bl[4], ahA[2], alA[2];
#pragma unroll
        for (int n = 0; n < 4; ++n) {
            int rB = wc * 64 + n * 16 + l15;
            bh[n] = *(const bf16x8*)(bufB + lch(rB, l4));
            bl[n] = *(const bf16x8*)(bufB + lch(rB, 4 + l4));
        }
#pragma unroll
        for (int i = 0; i < 2; ++i) {
            int rA = wr * 128 + i * 16 + l15;
            ahA[i] = *(const bf16x8*)(buf + lch(rA, l4));
            alA[i] = *(const bf16x8*)(buf + lch(rA, 4 + l4));
        }
        P_PRE;
#pragma unroll
        for (int i = 0; i < 2; ++i)
#pragma unroll
            for (int n = 0; n < 4; ++n) {
                f32x4 a = acc[i][n];
                a = MFMA_BF16(ahA[i], bh[n], a, 0, 0, 0);
                a = MFMA_BF16(ahA[i], bl[n], a, 0, 0, 0);
                a = MFMA_BF16(alA[i], bh[n], a, 0, 0, 0);
                acc[i][n] = a;
            }
        P_POST;
        // ---- P1: read A m2..m5; MFMA m2,m3 ----
        bf16x8 ahB[2], alB[2], ahC[2], alC[2];
#pragma unroll
        for (int i = 0; i < 2; ++i) {
            int rA = wr * 128 + (2 + i) * 16 + l15;
            ahB[i] = *(const bf16x8*)(buf + lch(rA, l4));
            alB[i] = *(const bf16x8*)(buf + lch(rA, 4 + l4));
        }
#pragma unroll
        for (int i = 0; i < 2; ++i) {
            int rA = wr * 128 + (4 + i) * 16 + l15;
            ahC[i] = *(const bf16x8*)(buf + lch(rA, l4));
            alC[i] = *(const bf16x8*)(buf + lch(rA, 4 + l4));
        }
        P_PRE;
#pragma unroll
        for (int i = 0; i < 2; ++i)
#pragma unroll
            for (int n = 0; n < 4; ++n) {
                f32x4 a = acc[2 + i][n];
                a = MFMA_BF16(ahB[i], bh[n], a, 0, 0, 0);
                a = MFMA_BF16(ahB[i], bl[n], a, 0, 0, 0);
                a = MFMA_BF16(alB[i], bh[n], a, 0, 0, 0);
                acc[2 + i][n] = a;
            }
        P_POST;
        // ---- P2: read A m6,m7; stage B(t+2); MFMA m4,m5 ----
        bf16x8 ahD[2], alD[2];
#pragma unroll
        for (int i = 0; i < 2; ++i) {
            int rA = wr * 128 + (6 + i) * 16 + l15;
            ahD[i] = *(const bf16x8*)(buf + lch(rA, l4));
            alD[i] = *(const bf16x8*)(buf + lch(rA, 4 + l4));
        }
        if (st) stageB4(Bt2, 2048ll, buf, tid);
        P_PRE;
#pragma unroll
        for (int i = 0; i < 2; ++i)
#pragma unroll
            for (int n = 0; n < 4; ++n) {
                f32x4 a = acc[4 + i][n];
                a = MFMA_BF16(ahC[i], bh[n], a, 0, 0, 0);
                a = MFMA_BF16(ahC[i], bl[n], a, 0, 0, 0);
                a = MFMA_BF16(alC[i], bh[n], a, 0, 0, 0);
                acc[4 + i][n] = a;
            }
        P_POST;
        // ---- P3: stage A(t+2); vmcnt; MFMA m6,m7 ----
        if (st) stageA4(At2, 2048ll, buf, tid);
        __builtin_amdgcn_s_setprio(1);
#pragma unroll
        for (int i = 0; i < 2; ++i)
#pragma unroll
            for (int n = 0; n < 4; ++n) {
                f32x4 a = acc[6 + i][n];
                a = MFMA_BF16(ahD[i], bh[n], a, 0, 0, 0);
                a = MFMA_BF16(ahD[i], bl[n], a, 0, 0, 0);
                a = MFMA_BF16(alD[i], bh[n], a, 0, 0, 0);
                acc[6 + i][n] = a;
            }
        __builtin_amdgcn_s_setprio(0);
        __builtin_amdgcn_sched_barrier(0);
        if (t + 2 < NT) {
            asm volatile("s_waitcnt vmcnt(8)" ::: "memory");
        } else if (t + 1 < NT) {
            asm volatile("s_waitcnt vmcnt(0)" ::: "memory");
        }
        __builtin_amdgcn_sched_barrier(0);
        __builtin_amdgcn_s_barrier();
    }
    int r0 = bx * 256 + wr * 128 + (l4 << 2);
    int c0 = by * 256 + wc * 64 + l15;
#pragma unroll
    for (int m = 0; m < 8; ++m)
#pragma unroll
        for (int n = 0; n < 4; ++n)
#pragma unroll
            for (int j = 0; j < 4; ++j) {
                int r = r0 + m * 16 + j;
                int c = c0 + n * 16;
                float v = acc[m][n][j];
                if (EPI == 0) {
                    Cs[(long long)z * sC + (long long)r * 1024 + c] = v;
                } else {
                    float rep;
                    bf16_t hb = to_bf16_rne(v, rep);
                    float res = v - rep;
                    float rep2;
                    bf16_t lb = to_bf16_rne(res, rep2);
                    long long rb = (long long)r * 2048 + ((c >> 5) << 6) + (c & 31);
                    Qint[rb] = hb;
                    Qint[rb + 32] = lb;
                    Qf[(long long)r * 1024 + c] = (_Float16)v;
                }
            }
}

// ---------- 256x256 dbuf f16 GEMM, 4-phase interleave (BK=64) ----------
// A rows K-contig (ldA), optional A-source switch at tile swt. B rows K-contig.
// EPI 0: f16 out (ld 1024, +z*sC). EPI 1: f32 tanh out (ld 1024).
template <int EPI>
__global__ __launch_bounds__(512, 2) void gemm_f16_256(
    const _Float16* __restrict__ A1, const _Float16* __restrict__ A2,
    const _Float16* __restrict__ B,
    long long ldA, long long ldB, long long sA, long long sB, long long sC,
    int NT, int swt, int nbx, int nby,
    _Float16* __restrict__ Cm, float* __restrict__ Co) {
    __shared__ _Float16 lds[65536];
    int tid = threadIdx.x, lane = tid & 63, wid = tid >> 6;
    int wr = wid >> 2, wc = wid & 3;
    int nwg = gridDim.x;
    int bid = blockIdx.x;
    int lid = (bid & 7) * (nwg >> 3) + (bid >> 3);
    int by = lid % nby;
    int t2_ = lid / nby;
    int bx = t2_ % nbx;
    int z = t2_ / nbx;
    const _Float16* A1t = A1 + (long long)z * sA + (long long)bx * 256 * ldA;
    const _Float16* A2t = A2 + (long long)bx * 256 * ldA;
    const _Float16* Bt = B + (long long)z * sB + (long long)by * 256 * ldB;
    stage2((0 < swt) ? A1t : A2t, ldA, Bt, ldB, lds, tid);
    stage2((1 < swt) ? A1t + 64 : A2t + (long long)(1 - swt) * 64, ldA, Bt + 64, ldB,
           lds + 32768, tid);
    f32x4 acc[8][4] = {};
    int l15 = lane & 15, l4 = lane >> 4;
    asm volatile("s_waitcnt vmcnt(8)" ::: "memory");
    __builtin_amdgcn_sched_barrier(0);
    __builtin_amdgcn_s_barrier();
    for (int t = 0; t < NT; ++t) {
        _Float16* buf = lds + (size_t)(t & 1) * 32768;
        _Float16* bufB = buf + 16384;
        int tt = t + 2;
        bool st = (tt < NT);
        const _Float16* gA2 =
            (tt < swt) ? A1t + (long long)tt * 64 : A2t + (long long)(tt - swt) * 64;
        const _Float16* gB2 = Bt + (long long)tt * 64;
        // ---- P0: read B all + A m0,m1; MFMA m0,m1 ----
        f16x8 bfr[4][2], aA[2][2];
#pragma unroll
        for (int n = 0; n < 4; ++n) {
            int rB = wc * 64 + n * 16 + l15;
#pragma unroll
            for (int ks = 0; ks < 2; ++ks)
                bfr[n][ks] = *(const f16x8*)(bufB + lch(rB, ks * 4 + l4));
        }
#pragma unroll
        for (int i = 0; i < 2; ++i) {
            int rA = wr * 128 + i * 16 + l15;
#pragma unroll
            for (int ks = 0; ks < 2; ++ks)
                aA[i][ks] = *(const f16x8*)(buf + lch(rA, ks * 4 + l4));
        }
        P_PRE;
#pragma unroll
        for (int i = 0; i < 2; ++i)
#pragma unroll
            for (int n = 0; n < 4; ++n) {
                f32x4 v = acc[i][n];
                v = MFMA_F16(aA[i][0], bfr[n][0], v, 0, 0, 0);
                v = MFMA_F16(aA[i][1], bfr[n][1], v, 0, 0, 0);
                acc[i][n] = v;
            }
        P_POST;
        // ---- P1: read A m2..m5; MFMA m2,m3 ----
        f16x8 aB[2][2], aC[2][2];
#pragma unroll
        for (int i = 0; i < 2; ++i) {
            int rA = wr * 128 + (2 + i) * 16 + l15;
#pragma unroll
            for (int ks = 0; ks < 2; ++ks)
                aB[i][ks] = *(const f16x8*)(buf + lch(rA, ks * 4 + l4));
        }
#pragma unroll
        for (int i = 0; i < 2; ++i) {
            int rA = wr * 128 + (4 + i) * 16 + l15;
#pragma unroll
            for (int ks = 0; ks < 2; ++ks)
                aC[i][ks] = *(const f16x8*)(buf + lch(rA, ks * 4 + l4));
        }
        P_PRE;
#pragma unroll
        for (int i = 0; i < 2; ++i)
#pragma unroll
            for (int n = 0; n < 4; ++n) {
                f32x4 v = acc[2 + i][n];
                v = MFMA_F16(aB[i][0], bfr[n][0], v, 0, 0, 0);
                v = MFMA_F16(aB[i][1], bfr[n][1], v, 0, 0, 0);
                acc[2 + i][n] = v;
            }
        P_POST;
        // ---- P2: read A m6,m7; stage B(t+2); MFMA m4,m5 ----
        f16x8 aD[2][2];
#pragma unroll
        for (int i = 0; i < 2; ++i) {
            int rA = wr * 128 + (6 + i) * 16 + l15;
#pragma unroll
            for (int ks = 0; ks < 2; ++ks)
                aD[i][ks] = *(const f16x8*)(buf + lch(rA, ks * 4 + l4));
        }
        if (st) stageB4(gB2, ldB, buf, tid);
        P_PRE;
#pragma unroll
        for (int i = 0; i < 2; ++i)
#pragma unroll
            for (int n = 0; n < 4; ++n) {
                f32x4 v = acc[4 + i][n];
                v = MFMA_F16(aC[i][0], bfr[n][0], v, 0, 0, 0);
                v = MFMA_F16(aC[i][1], bfr[n][1], v, 0, 0, 0);
                acc[4 + i][n] = v;
            }
        P_POST;
        // ---- P3: stage A(t+2); MFMA m6,m7; vmcnt ----
        if (st) stageA4(gA2, ldA, buf, tid);
        __builtin_amdgcn_s_setprio(1);
#pragma unroll
        for (int i = 0; i < 2; ++i)
#pragma unroll
            for (int n = 0; n < 4; ++n) {
                f32x4 v = acc[6 + i][n];
                v = MFMA_F16(aD[i][0], bfr[n][0], v, 0, 0, 0);
                v = MFMA_F16(aD[i][1], bfr[n][1], v, 0, 0, 0);
                acc[6 + i][n] = v;
            }
        __builtin_amdgcn_s_setprio(0);
        __builtin_amdgcn_sched_barrier(0);
        if (t + 2 < NT) {
            asm volatile("s_waitcnt vmcnt(8)" ::: "memory");
        } else if (t + 1 < NT) {
            asm volatile("s_waitcnt vmcnt(0)" ::: "memory");
        }
        __builtin_amdgcn_sched_barrier(0);
        __builtin_amdgcn_s_barrier();
    }
    int r0 = bx * 256 + wr * 128 + (l4 << 2);
    int c0 = by * 256 + wc * 64 + l15;
#pragma unroll
    for (int m = 0; m < 8; ++m)
#pragma unroll
        for (int n = 0; n < 4; ++n)
#pragma unroll
            for (int j = 0; j < 4; ++j) {
                int r = r0 + m * 16 + j;
                int c = c0 + n * 16;
                float v = acc[m][n][j];
                if (EPI == 0) {
                    Cm[(long long)z * sC + (long long)r * 1024 + c] = (_Float16)v;
                } else {
                    Co[(long long)r * 1024 + c] = tanhf(v);
                }
            }
}

// ---------- launch ----------

extern "C" void kernel_launch(void* const* d_in, const int* in_sizes, int n_in,
                              void* d_out, int out_size, void* d_ws, size_t ws_size,
                              hipStream_t stream) {
    const float* query = (const float*)d_in[0];
    const float* ctx = (const float*)d_in[1];
    const int* mask = (const int*)d_in[2];
    const float* Win = (const float*)d_in[3];
    const float* Wout = (const float*)d_in[4];
    float* outp = (float*)d_out;

    const long long MB = 1048576ll;
    // footprint: exactly 16G MiB (weights overlaid into dead slab regions).
    int G = 1;
    if ((long long)ws_size >= 512 * MB) G = 32;
    else if ((long long)ws_size >= 256 * MB) G = 16;
    else if ((long long)ws_size >= 128 * MB) G = 8;
    else if ((long long)ws_size >= 64 * MB) G = 4;
    else if ((long long)ws_size >= 32 * MB) G = 2;

    char* p = (char*)d_ws;
    const long long R = (long long)G * 1024;   // rows per chunk
    bf16_t* qint = (bf16_t*)p; p += 4 * G * MB;    // [R][2048] interleaved
    _Float16* qf = (_Float16*)p; p += 2 * G * MB;  // [R][1024]
    // slabA (4G MiB): win_int (4 MiB, GEMM1) -> ctx_int [R][2048] (GEMM2)
    //                 -> wf [R][1024] (lower 2G) + mixf [R][1024] (upper 2G)
    char* slabA = p; p += 4 * G * MB;
    bf16_t* win_int = (bf16_t*)slabA;
    bf16_t* ctx_int = (bf16_t*)slabA;
    _Float16* wf = (_Float16*)slabA;
    _Float16* mixf = (_Float16*)(slabA + 2 * G * MB);
    _Float16* ctxT = (_Float16*)p; p += 2 * G * MB;
    // slabC (4G MiB): qs_int (GEMM1 A) -> scores f32 (GEMM2/softmax) -> woutf (GEMM4 B)
    char* slabC = p;
    bf16_t* qs_int = (bf16_t*)slabC;
    float* scores = (float*)slabC;
    _Float16* woutf = (_Float16*)slabC;

    const long long LD = 1048576ll;  // 1024*1024 elements

    for (int b0 = 0; b0 < 32; b0 += G) {
        const float* qsrc = query + (long long)b0 * LD;
        const float* csrc = ctx + (long long)b0 * LD;
        // weights + query prep (win_int lives in slabA until prep_ctx overwrites it)
        split_int_k<<<1024, 256, 0, stream>>>(Win, win_int, 262144ll);
        split_int_k<<<(int)R, 256, 0, stream>>>(qsrc, qs_int, R * 256);
        // GEMM1: q = query @ Win^T (bf16x3) -> qint (interleaved) + qf (f16)
        gemm_x3_256<1><<<16 * G, 512, 0, stream>>>(
            qs_int, win_int, 0, 0, 0, 4 * G, 4, nullptr, qint, qf);
        // fused ctx prep: ctx_int (over win_int, dead) + ctxT, reads ctx once
        prep_ctx_k<<<dim3(32, 32, G), dim3(32, 8, 1), 0, stream>>>(csrc, ctx_int, ctxT);
        // GEMM2: scores = q @ ctx^T (bf16x3) -> scores (over qs_int, dead)
        gemm_x3_256<0><<<16 * G, 512, 0, stream>>>(
            qint, ctx_int, 2097152ll, 2097152ll, 1048576ll, 4, 4,
            scores, nullptr, nullptr);
        // softmax -> wf (over ctx_int lower half, dead)
        masked_softmax_k<<<(int)R, 256, 0, stream>>>(
            scores, mask + (long long)b0 * 1024 * 1024, wf);
        // Wout cast -> woutf (over scores, dead)
        cast_f16_k<<<2048, 256, 0, stream>>>(Wout, woutf, 524288ll);
        // GEMM3: mix = w @ ctxT^T (f16) -> mixf (over ctx_int upper half, dead)
        gemm_f16_256<0><<<16 * G, 512, 0, stream>>>(
            wf, wf, ctxT, 1024ll, 1024ll, 1048576ll, 1048576ll, 1048576ll,
            16, 1 << 20, 4, 4, mixf, nullptr);
        // GEMM4: out = tanh(mix @ W1^T + q @ W2^T), K=2048, A-switch at tile 16
        gemm_f16_256<1><<<16 * G, 512, 0, stream>>>(
            mixf, qf, woutf, 1024ll, 2048ll, 0, 0, 0,
            32, 16, 4 * G, 4, nullptr, outp + (long long)b0 * LD);
    }
}